// Round 17
// baseline (461.733 us; speedup 1.0000x reference)
//
#include <hip/hip_runtime.h>
#include <hip/hip_bf16.h>
#include <math.h>

typedef __bf16 bf16_t;
typedef bf16_t bf16x8 __attribute__((ext_vector_type(8)));
typedef float  f32x4  __attribute__((ext_vector_type(4)));

static constexpr int Bn = 16384;
static constexpr int Hn = 512;

__device__ __forceinline__ float sigm(float x) { return 1.0f / (1.0f + __expf(-x)); }

typedef __attribute__((address_space(3))) void lds_void;
typedef const __attribute__((address_space(1))) void gl_void;

__device__ __forceinline__ void glds16(const void* g, void* l) {
    __builtin_amdgcn_global_load_lds((gl_void*)g, (lds_void*)l, 16, 0, 0);
}

// Fused prologue: blocks [0,8192) convert comb; [8192,14336) do the 3 transposes.
__global__ void prologue(const float* __restrict__ inp, const float* __restrict__ hid,
                         bf16_t* __restrict__ comb,
                         const float* __restrict__ Wg, bf16_t* __restrict__ WgT,
                         const float* __restrict__ Wa, bf16_t* __restrict__ WaT,
                         const float* __restrict__ Mem, bf16_t* __restrict__ MemT)
{
    int b = blockIdx.x;
    if (b < 8192) {
        size_t t = (size_t)b * blockDim.x + threadIdx.x;
        size_t r = t >> 7;
        int c8 = (int)(t & 127);
        const float* src = (c8 < 64) ? (inp + r * 512 + c8 * 8) : (hid + r * 512 + (c8 - 64) * 8);
        float4 a = ((const float4*)src)[0];
        float4 bb = ((const float4*)src)[1];
        bf16x8 o;
        o[0] = (bf16_t)a.x; o[1] = (bf16_t)a.y; o[2] = (bf16_t)a.z; o[3] = (bf16_t)a.w;
        o[4] = (bf16_t)bb.x; o[5] = (bf16_t)bb.y; o[6] = (bf16_t)bb.z; o[7] = (bf16_t)bb.w;
        *(bf16x8*)(comb + t * 8) = o;
        return;
    }
    b -= 8192;
    __shared__ float tile[32][33];
    const float* src; bf16_t* dst; int R, C, gx;
    if (b < 2048)      { src = Wg;  dst = WgT;  R = 1024; C = 2048; gx = 64; }
    else if (b < 4096) { b -= 2048; src = Wa;  dst = WaT;  R = 512;  C = 4096; gx = 128; }
    else               { b -= 4096; src = Mem; dst = MemT; R = 4096; C = 512;  gx = 16; }
    const int x0 = (b % gx) * 32, y0 = (b / gx) * 32;
    const int tx = threadIdx.x & 31, ty = threadIdx.x >> 5;
#pragma unroll
    for (int i = 0; i < 32; i += 8)
        tile[ty + i][tx] = src[(size_t)(y0 + ty + i) * C + x0 + tx];
    __syncthreads();
#pragma unroll
    for (int i = 0; i < 32; i += 8)
        dst[(size_t)(x0 + ty + i) * R + y0 + tx] = (bf16_t)tile[tx][ty + i];
}

// C[M,N] = epi(A @ Bt^T + bias). 128x256 tile, BK=64, 8 waves (2x4), 512 threads.
// Proven structure: single-buffer, 2 barriers/K-tile, zero bank conflicts.
// EPI 0: activated gates -> bout stride 2048. EPI 1: E = exp(logit+ba) -> bout stride ost.
template<int EPI>
__global__ __launch_bounds__(512)
void gemm_w8(const bf16_t* __restrict__ A, int lda,
             const bf16_t* __restrict__ Bt, int ldb,
             const float* __restrict__ bias, int K, int N,
             bf16_t* __restrict__ bout, int ost)
{
    __shared__ __align__(16) bf16_t sA[128 * 64];   // 16 KB
    __shared__ __align__(16) bf16_t sB[256 * 64];   // 32 KB

    const int tid = threadIdx.x, lane = tid & 63, wid = tid >> 6;
    const int wr = wid >> 2, wc = wid & 3;          // 2x4 waves

    const int nwg = gridDim.x;
    int bid = (blockIdx.x & 7) * (nwg >> 3) + (blockIdx.x >> 3);  // XCD swizzle
    const int cbn = N >> 8;
    const int row0 = (bid / cbn) * 128, col0 = (bid % cbn) * 256;

    f32x4 acc[4][4] = {};
    const int nk = K >> 6;
    const int l15 = lane & 15, kq = lane >> 4;

    for (int kt = 0; kt < nk; ++kt) {
        const int k0 = kt << 6;
        {
            const int slot = (lane & 7) ^ (lane >> 3);
#pragma unroll
            for (int t = 0; t < 2; ++t) {
                const int c8 = wid * 2 + t;
                const int r = c8 * 8 + (lane >> 3);
                glds16(A + (size_t)(row0 + r) * lda + k0 + slot * 8, sA + c8 * 512);
            }
#pragma unroll
            for (int t = 0; t < 4; ++t) {
                const int c8 = wid * 4 + t;
                const int r = c8 * 8 + (lane >> 3);
                glds16(Bt + (size_t)(col0 + r) * ldb + k0 + slot * 8, sB + c8 * 512);
            }
        }
        __syncthreads();
#pragma unroll
        for (int ks = 0; ks < 2; ++ks) {
            bf16x8 af[4], bfr[4];
            const int slot = (ks * 4 + kq) ^ (l15 & 7);
#pragma unroll
            for (int j = 0; j < 4; ++j) {
                const int rb = wc * 64 + j * 16 + l15;
                bfr[j] = *(const bf16x8*)&sB[rb * 64 + slot * 8];
                const int ra = wr * 64 + j * 16 + l15;
                af[j] = *(const bf16x8*)&sA[ra * 64 + slot * 8];
            }
#pragma unroll
            for (int i = 0; i < 4; ++i)
#pragma unroll
                for (int j = 0; j < 4; ++j)
                    acc[i][j] = __builtin_amdgcn_mfma_f32_16x16x32_bf16(af[i], bfr[j], acc[i][j], 0, 0, 0);
        }
        __syncthreads();
    }

    const int lr = (lane >> 4) * 4, lc = lane & 15;
#pragma unroll
    for (int i = 0; i < 4; ++i) {
#pragma unroll
        for (int j = 0; j < 4; ++j) {
#pragma unroll
            for (int r = 0; r < 4; ++r) {
                const int grow = row0 + wr * 64 + i * 16 + lr + r;
                const int gcol = col0 + wc * 64 + j * 16 + lc;
                float v = acc[i][j][r] + bias[gcol];
                if constexpr (EPI == 0) {
                    const float a = ((gcol >> 9) == 2) ? tanhf(v) : sigm(v);
                    bout[(size_t)grow * 2048 + gcol] = (bf16_t)a;
                } else {
                    bout[(size_t)grow * ost + gcol] = (bf16_t)__expf(v);
                }
            }
        }
    }
}

// mr = (E @ MemT^T)/denom fused with LSTM update; denom = rowsum(E) via ones-MFMA.
// 64x128 tile, BK=64, 8 waves (2x4, wave tile 32x32), 24 KB LDS, grid 1024 = 4 blocks/CU.
// The 4 col-blocks of each row panel are mapped to the SAME XCD (panel = (j>>2)*8+xcd)
// so their shared E-panel reads hit L2. If attnOut != null (big-ws): each block also
// writes attn = E/denom for its quarter of the columns (disjoint, race-free).
__global__ __launch_bounds__(512)
void gemm3o(const bf16_t* __restrict__ E, int estride,
            const bf16_t* __restrict__ MemT,
            const bf16_t* __restrict__ gates, const float* __restrict__ cell,
            float* __restrict__ fout, float* __restrict__ denomBuf,
            float* __restrict__ attnOut)
{
    __shared__ __align__(16) bf16_t sA[64 * 64];    // 8 KB
    __shared__ __align__(16) bf16_t sB[128 * 64];   // 16 KB

    const int tid = threadIdx.x, lane = tid & 63, wid = tid >> 6;
    const int wr = wid >> 2, wc = wid & 3;

    // panel-grouped XCD mapping: 4 col-blocks of a panel share an XCD
    const int idx = blockIdx.x;                     // 1024 blocks
    const int xcd = idx & 7, j = idx >> 3;          // j 0..127
    const int colh = j & 3;
    const int panel = (j >> 2) * 8 + xcd;           // 0..255
    const int row0 = panel * 64, col0 = colh * 128;

    f32x4 acc[2][2] = {};
    f32x4 dacc[2] = {};
    const int l15 = lane & 15, kq = lane >> 4;

    bf16x8 ones;
#pragma unroll
    for (int e = 0; e < 8; ++e) ones[e] = (bf16_t)1.0f;

    for (int kt = 0; kt < 64; ++kt) {
        const int k0 = kt << 6;
        const int slot = (lane & 7) ^ (lane >> 3);
        {   // A: 8 chunks, 1/wave
            const int c8 = wid;
            const int r = c8 * 8 + (lane >> 3);
            glds16(E + (size_t)(row0 + r) * estride + k0 + slot * 8, sA + c8 * 512);
        }
#pragma unroll
        for (int t = 0; t < 2; ++t) {               // B: 16 chunks, 2/wave
            const int c8 = wid * 2 + t;
            const int r = c8 * 8 + (lane >> 3);
            glds16(MemT + (size_t)(col0 + r) * 4096 + k0 + slot * 8, sB + c8 * 512);
        }
        __syncthreads();
#pragma unroll
        for (int ks = 0; ks < 2; ++ks) {
            bf16x8 af[2], bfr[2];
            const int sl = (ks * 4 + kq) ^ (l15 & 7);
#pragma unroll
            for (int jj = 0; jj < 2; ++jj) {
                const int rb = wc * 32 + jj * 16 + l15;
                bfr[jj] = *(const bf16x8*)&sB[rb * 64 + sl * 8];
            }
#pragma unroll
            for (int i = 0; i < 2; ++i) {
                const int ra = wr * 32 + i * 16 + l15;
                af[i] = *(const bf16x8*)&sA[ra * 64 + sl * 8];
            }
#pragma unroll
            for (int i = 0; i < 2; ++i) {
#pragma unroll
                for (int jj = 0; jj < 2; ++jj)
                    acc[i][jj] = __builtin_amdgcn_mfma_f32_16x16x32_bf16(af[i], bfr[jj], acc[i][jj], 0, 0, 0);
                dacc[i] = __builtin_amdgcn_mfma_f32_16x16x32_bf16(af[i], ones, dacc[i], 0, 0, 0);
            }
        }
        __syncthreads();
    }

    const int lr = (lane >> 4) * 4, lc = lane & 15;

    // denom: colh==0, wc==0 waves cover rows row0 + wr*32 + i*16 + lr + r
    if (colh == 0 && wc == 0 && l15 == 0) {
#pragma unroll
        for (int i = 0; i < 2; ++i)
#pragma unroll
            for (int r = 0; r < 4; ++r)
                denomBuf[row0 + wr * 32 + i * 16 + lr + r] = dacc[i][r];
    }

    float invd[2][4];
#pragma unroll
    for (int i = 0; i < 2; ++i)
#pragma unroll
        for (int r = 0; r < 4; ++r) invd[i][r] = 1.0f / dacc[i][r];

#pragma unroll
    for (int i = 0; i < 2; ++i) {
#pragma unroll
        for (int jj = 0; jj < 2; ++jj) {
#pragma unroll
            for (int r = 0; r < 4; ++r) {
                const int grow = row0 + wr * 32 + i * 16 + lr + r;
                const int gcol = col0 + wc * 32 + jj * 16 + lc;
                const float v = acc[i][jj][r] * invd[i][r];      // memory_read
                const float ig = (float)gates[(size_t)grow * 2048 + gcol];
                const float fg = (float)gates[(size_t)grow * 2048 + 512 + gcol];
                const float cg = (float)gates[(size_t)grow * 2048 + 1024 + gcol];
                const float og = (float)gates[(size_t)grow * 2048 + 1536 + gcol];
                const float cv = cell[(size_t)grow * 512 + gcol];
                const float ncv = fg * cv + ig * cg + 0.1f * v;
                fout[(size_t)grow * 512 + gcol] = og * tanhf(ncv);
                fout[(size_t)Bn * Hn + (size_t)grow * 512 + gcol] = ncv;
            }
        }
    }

    // ---- fused attn write (big-ws path): this block writes attn = E/denom for its
    // row panel and its quarter of the columns. E re-read is L2-hot from the K-loop.
    if (attnOut) {
        float* sDen = (float*)sA;                   // reuse sA (K-loop fully drained)
        __syncthreads();
        if (wc == 0 && l15 == 0) {
#pragma unroll
            for (int i = 0; i < 2; ++i)
#pragma unroll
                for (int r = 0; r < 4; ++r)
                    sDen[wr * 32 + i * 16 + lr + r] = invd[i][r];
        }
        __syncthreads();
        const int colbase = colh * 1024;
        const bf16_t* Eb = E + (size_t)row0 * estride + colbase;
        float* ab = attnOut + (size_t)row0 * 4096 + colbase;
        // 64 rows x 1024 cols; 512 threads, 16B E-read / 32B attn-write per step
        for (int c = tid; c < 64 * 128; c += 512) {
            const int rr = c >> 7, ch = c & 127;
            bf16x8 e8 = *(const bf16x8*)(Eb + (size_t)rr * estride + ch * 8);
            const float inv = sDen[rr];
            float* rp = ab + (size_t)rr * 4096 + ch * 8;
            float4 o0 = { (float)e8[0] * inv, (float)e8[1] * inv,
                          (float)e8[2] * inv, (float)e8[3] * inv };
            float4 o1 = { (float)e8[4] * inv, (float)e8[5] * inv,
                          (float)e8[6] * inv, (float)e8[7] * inv };
            *(float4*)rp = o0;
            *((float4*)rp + 1) = o1;
        }
    }
}

// attn[row] = E[row] / denom[row]. Fallback for the small-ws (packed in d_out) path.
__global__ __launch_bounds__(512)
void attn_writer(const bf16_t* __restrict__ E, int estride,
                 const float* __restrict__ denom, float* __restrict__ attn)
{
    const int row = blockIdx.x * 2 + (threadIdx.x >> 8);
    const int t = threadIdx.x & 255;
    const bf16_t* lp = E + (size_t)row * estride;
    const float inv = 1.0f / denom[row];
    bf16x8 a = ((const bf16x8*)lp)[2 * t];
    bf16x8 b = ((const bf16x8*)lp)[2 * t + 1];
    __syncthreads();
    float* rp = attn + (size_t)row * 4096;
    float4 o0 = { (float)a[0] * inv, (float)a[1] * inv, (float)a[2] * inv, (float)a[3] * inv };
    float4 o1 = { (float)a[4] * inv, (float)a[5] * inv, (float)a[6] * inv, (float)a[7] * inv };
    float4 o2 = { (float)b[0] * inv, (float)b[1] * inv, (float)b[2] * inv, (float)b[3] * inv };
    float4 o3 = { (float)b[4] * inv, (float)b[5] * inv, (float)b[6] * inv, (float)b[7] * inv };
    ((float4*)rp)[4 * t]     = o0;
    ((float4*)rp)[4 * t + 1] = o1;
    ((float4*)rp)[4 * t + 2] = o2;
    ((float4*)rp)[4 * t + 3] = o3;
}

extern "C" void kernel_launch(void* const* d_in, const int* in_sizes, int n_in,
                              void* d_out, int out_size, void* d_ws, size_t ws_size,
                              hipStream_t stream)
{
    const float* input  = (const float*)d_in[0];
    const float* hidden = (const float*)d_in[1];
    const float* cell   = (const float*)d_in[2];
    const float* Wg     = (const float*)d_in[3];
    const float* bg     = (const float*)d_in[4];
    const float* Wa     = (const float*)d_in[5];
    const float* ba     = (const float*)d_in[6];
    const float* Mem    = (const float*)d_in[7];

    float* out  = (float*)d_out;
    float* attn = out + 2ull * Bn * Hn;

    bf16_t* comb  = (bf16_t*)d_ws;                 // [B][1024]      33.5 MB
    bf16_t* WgT   = comb + (size_t)Bn * 1024;      // [2048][1024]    4.2
    bf16_t* WaT   = WgT + (size_t)2048 * 1024;     // [4096][512]     4.2
    bf16_t* MemT  = WaT + (size_t)4096 * 512;      // [512][4096]     4.2
    bf16_t* gates = MemT + (size_t)512 * 4096;     // [B][2048]      67.1
    float*  denom = (float*)(gates + (size_t)Bn * 2048);   // [B] f32   0.07
    bf16_t* pws   = (bf16_t*)(denom + Bn);         // [B][4096]     134.2 (big path)

    const size_t need_big = (size_t)((char*)(pws + (size_t)Bn * 4096) - (char*)d_ws);
    const bool big = ws_size >= need_big;
    bf16_t* Ebuf = big ? pws : (bf16_t*)attn;      // E = exp(logits), bf16
    const int estride = big ? 4096 : 8192;

    // convert + transposes in one launch
    prologue<<<14336, 256, 0, stream>>>(input, hidden, comb, Wg, WgT, Wa, WaT, Mem, MemT);

    // E = exp(h @ Wa + ba): 128x256 tiles, grid 128x16
    gemm_w8<1><<<2048, 512, 0, stream>>>(comb + 512, 1024, WaT, 512, ba, 512, 4096,
                                         Ebuf, estride);
    // gates = act([x|h] @ Wg + bg): 128x256 tiles, grid 128x8
    gemm_w8<0><<<1024, 512, 0, stream>>>(comb, 1024, WgT, 1024, bg, 1024, 2048, gates, 2048);

    // mr = (E @ Mem)/rowsum(E) fused with LSTM update; denom via ones-MFMA.
    // 64x128 tiles, grid 1024 = 4 blocks/CU; big-ws: attn write fused into the tail.
    gemm3o<<<1024, 512, 0, stream>>>(Ebuf, estride, MemT, gates, cell, out, denom,
                                     big ? attn : nullptr);

    if (!big) attn_writer<<<8192, 512, 0, stream>>>(Ebuf, estride, denom, attn);
}

// Round 18
// 418.580 us; speedup vs baseline: 1.1031x; 1.1031x over previous
//
#include <hip/hip_runtime.h>
#include <hip/hip_bf16.h>
#include <math.h>

typedef __bf16 bf16_t;
typedef bf16_t bf16x8 __attribute__((ext_vector_type(8)));
typedef float  f32x4  __attribute__((ext_vector_type(4)));

static constexpr int Bn = 16384;
static constexpr int Hn = 512;

__device__ __forceinline__ float sigm(float x) { return 1.0f / (1.0f + __expf(-x)); }

typedef __attribute__((address_space(3))) void lds_void;
typedef const __attribute__((address_space(1))) void gl_void;

__device__ __forceinline__ void glds16(const void* g, void* l) {
    __builtin_amdgcn_global_load_lds((gl_void*)g, (lds_void*)l, 16, 0, 0);
}

// Fused prologue: blocks [0,8192) convert comb; [8192,14336) do the 3 transposes.
__global__ void prologue(const float* __restrict__ inp, const float* __restrict__ hid,
                         bf16_t* __restrict__ comb,
                         const float* __restrict__ Wg, bf16_t* __restrict__ WgT,
                         const float* __restrict__ Wa, bf16_t* __restrict__ WaT,
                         const float* __restrict__ Mem, bf16_t* __restrict__ MemT)
{
    int b = blockIdx.x;
    if (b < 8192) {
        size_t t = (size_t)b * blockDim.x + threadIdx.x;
        size_t r = t >> 7;
        int c8 = (int)(t & 127);
        const float* src = (c8 < 64) ? (inp + r * 512 + c8 * 8) : (hid + r * 512 + (c8 - 64) * 8);
        float4 a = ((const float4*)src)[0];
        float4 bb = ((const float4*)src)[1];
        bf16x8 o;
        o[0] = (bf16_t)a.x; o[1] = (bf16_t)a.y; o[2] = (bf16_t)a.z; o[3] = (bf16_t)a.w;
        o[4] = (bf16_t)bb.x; o[5] = (bf16_t)bb.y; o[6] = (bf16_t)bb.z; o[7] = (bf16_t)bb.w;
        *(bf16x8*)(comb + t * 8) = o;
        return;
    }
    b -= 8192;
    __shared__ float tile[32][33];
    const float* src; bf16_t* dst; int R, C, gx;
    if (b < 2048)      { src = Wg;  dst = WgT;  R = 1024; C = 2048; gx = 64; }
    else if (b < 4096) { b -= 2048; src = Wa;  dst = WaT;  R = 512;  C = 4096; gx = 128; }
    else               { b -= 4096; src = Mem; dst = MemT; R = 4096; C = 512;  gx = 16; }
    const int x0 = (b % gx) * 32, y0 = (b / gx) * 32;
    const int tx = threadIdx.x & 31, ty = threadIdx.x >> 5;
#pragma unroll
    for (int i = 0; i < 32; i += 8)
        tile[ty + i][tx] = src[(size_t)(y0 + ty + i) * C + x0 + tx];
    __syncthreads();
#pragma unroll
    for (int i = 0; i < 32; i += 8)
        dst[(size_t)(x0 + ty + i) * R + y0 + tx] = (bf16_t)tile[tx][ty + i];
}

// C[M,N] = epi(A @ Bt^T + bias). 128x256 tile, BK=64, 8 waves (2x4), 512 threads.
// Proven structure: single-buffer, 2 barriers/K-tile, zero bank conflicts.
// EPI 0: activated gates -> bout stride 2048. EPI 1: E = exp(logit+ba) -> bout stride ost.
template<int EPI>
__global__ __launch_bounds__(512)
void gemm_w8(const bf16_t* __restrict__ A, int lda,
             const bf16_t* __restrict__ Bt, int ldb,
             const float* __restrict__ bias, int K, int N,
             bf16_t* __restrict__ bout, int ost)
{
    __shared__ __align__(16) bf16_t sA[128 * 64];   // 16 KB
    __shared__ __align__(16) bf16_t sB[256 * 64];   // 32 KB

    const int tid = threadIdx.x, lane = tid & 63, wid = tid >> 6;
    const int wr = wid >> 2, wc = wid & 3;          // 2x4 waves

    const int nwg = gridDim.x;
    int bid = (blockIdx.x & 7) * (nwg >> 3) + (blockIdx.x >> 3);  // XCD swizzle
    const int cbn = N >> 8;
    const int row0 = (bid / cbn) * 128, col0 = (bid % cbn) * 256;

    f32x4 acc[4][4] = {};
    const int nk = K >> 6;
    const int l15 = lane & 15, kq = lane >> 4;

    for (int kt = 0; kt < nk; ++kt) {
        const int k0 = kt << 6;
        {
            const int slot = (lane & 7) ^ (lane >> 3);
#pragma unroll
            for (int t = 0; t < 2; ++t) {
                const int c8 = wid * 2 + t;
                const int r = c8 * 8 + (lane >> 3);
                glds16(A + (size_t)(row0 + r) * lda + k0 + slot * 8, sA + c8 * 512);
            }
#pragma unroll
            for (int t = 0; t < 4; ++t) {
                const int c8 = wid * 4 + t;
                const int r = c8 * 8 + (lane >> 3);
                glds16(Bt + (size_t)(col0 + r) * ldb + k0 + slot * 8, sB + c8 * 512);
            }
        }
        __syncthreads();
#pragma unroll
        for (int ks = 0; ks < 2; ++ks) {
            bf16x8 af[4], bfr[4];
            const int slot = (ks * 4 + kq) ^ (l15 & 7);
#pragma unroll
            for (int j = 0; j < 4; ++j) {
                const int rb = wc * 64 + j * 16 + l15;
                bfr[j] = *(const bf16x8*)&sB[rb * 64 + slot * 8];
                const int ra = wr * 64 + j * 16 + l15;
                af[j] = *(const bf16x8*)&sA[ra * 64 + slot * 8];
            }
#pragma unroll
            for (int i = 0; i < 4; ++i)
#pragma unroll
                for (int j = 0; j < 4; ++j)
                    acc[i][j] = __builtin_amdgcn_mfma_f32_16x16x32_bf16(af[i], bfr[j], acc[i][j], 0, 0, 0);
        }
        __syncthreads();
    }

    const int lr = (lane >> 4) * 4, lc = lane & 15;
#pragma unroll
    for (int i = 0; i < 4; ++i) {
#pragma unroll
        for (int j = 0; j < 4; ++j) {
#pragma unroll
            for (int r = 0; r < 4; ++r) {
                const int grow = row0 + wr * 64 + i * 16 + lr + r;
                const int gcol = col0 + wc * 64 + j * 16 + lc;
                float v = acc[i][j][r] + bias[gcol];
                if constexpr (EPI == 0) {
                    const float a = ((gcol >> 9) == 2) ? tanhf(v) : sigm(v);
                    bout[(size_t)grow * 2048 + gcol] = (bf16_t)a;
                } else {
                    bout[(size_t)grow * ost + gcol] = (bf16_t)__expf(v);
                }
            }
        }
    }
}

// mr = (E @ MemT^T)/denom fused with LSTM update; denom = rowsum(E) via ones-MFMA.
// 64x256 tile, BK=64, 8 waves (2x4), 40 KB LDS, grid 512 (proven geometry).
// If attnOut != null (big-ws path): the two col-blocks of each row panel also write
// attn = E/denom for their half of the columns (disjoint, race-free), and the
// separate attn_writer pass is skipped.
__global__ __launch_bounds__(512)
void gemm3o(const bf16_t* __restrict__ E, int estride,
            const bf16_t* __restrict__ MemT,
            const bf16_t* __restrict__ gates, const float* __restrict__ cell,
            float* __restrict__ fout, float* __restrict__ denomBuf,
            float* __restrict__ attnOut)
{
    __shared__ __align__(16) bf16_t sA[64 * 64];    // 8 KB
    __shared__ __align__(16) bf16_t sB[256 * 64];   // 32 KB

    const int tid = threadIdx.x, lane = tid & 63, wid = tid >> 6;
    const int wr = wid >> 2, wc = wid & 3;

    int bid = (blockIdx.x & 7) * 64 + (blockIdx.x >> 3);   // 512 blocks, XCD swizzle
    const int row0 = (bid >> 1) * 64, col0 = (bid & 1) * 256;

    f32x4 acc[2][4] = {};
    f32x4 dacc[2] = {};
    const int l15 = lane & 15, kq = lane >> 4;

    bf16x8 ones;
#pragma unroll
    for (int e = 0; e < 8; ++e) ones[e] = (bf16_t)1.0f;

    for (int kt = 0; kt < 64; ++kt) {
        const int k0 = kt << 6;
        const int slot = (lane & 7) ^ (lane >> 3);
        {   // A: 8 chunks, 1/wave
            const int c8 = wid;
            const int r = c8 * 8 + (lane >> 3);
            glds16(E + (size_t)(row0 + r) * estride + k0 + slot * 8, sA + c8 * 512);
        }
#pragma unroll
        for (int t = 0; t < 4; ++t) {               // B: 32 chunks, 4/wave
            const int c8 = wid * 4 + t;
            const int r = c8 * 8 + (lane >> 3);
            glds16(MemT + (size_t)(col0 + r) * 4096 + k0 + slot * 8, sB + c8 * 512);
        }
        __syncthreads();
#pragma unroll
        for (int ks = 0; ks < 2; ++ks) {
            bf16x8 af[2], bfr[4];
            const int sl = (ks * 4 + kq) ^ (l15 & 7);
#pragma unroll
            for (int j = 0; j < 4; ++j) {
                const int rb = wc * 64 + j * 16 + l15;
                bfr[j] = *(const bf16x8*)&sB[rb * 64 + sl * 8];
            }
#pragma unroll
            for (int i = 0; i < 2; ++i) {
                const int ra = wr * 32 + i * 16 + l15;
                af[i] = *(const bf16x8*)&sA[ra * 64 + sl * 8];
            }
#pragma unroll
            for (int i = 0; i < 2; ++i) {
#pragma unroll
                for (int j = 0; j < 4; ++j)
                    acc[i][j] = __builtin_amdgcn_mfma_f32_16x16x32_bf16(af[i], bfr[j], acc[i][j], 0, 0, 0);
                dacc[i] = __builtin_amdgcn_mfma_f32_16x16x32_bf16(af[i], ones, dacc[i], 0, 0, 0);
            }
        }
        __syncthreads();
    }

    const int lr = (lane >> 4) * 4, lc = lane & 15;

    // denom: wc==0 waves of col-block 0 cover rows row0 + wr*32 + i*16 + lr + r
    if (col0 == 0 && wc == 0 && l15 == 0) {
#pragma unroll
        for (int i = 0; i < 2; ++i)
#pragma unroll
            for (int r = 0; r < 4; ++r)
                denomBuf[row0 + wr * 32 + i * 16 + lr + r] = dacc[i][r];
    }

    float invd[2][4];
#pragma unroll
    for (int i = 0; i < 2; ++i)
#pragma unroll
        for (int r = 0; r < 4; ++r) invd[i][r] = 1.0f / dacc[i][r];

#pragma unroll
    for (int i = 0; i < 2; ++i) {
#pragma unroll
        for (int j = 0; j < 4; ++j) {
#pragma unroll
            for (int r = 0; r < 4; ++r) {
                const int grow = row0 + wr * 32 + i * 16 + lr + r;
                const int gcol = col0 + wc * 64 + j * 16 + lc;
                const float v = acc[i][j][r] * invd[i][r];       // memory_read
                const float ig = (float)gates[(size_t)grow * 2048 + gcol];
                const float fg = (float)gates[(size_t)grow * 2048 + 512 + gcol];
                const float cg = (float)gates[(size_t)grow * 2048 + 1024 + gcol];
                const float og = (float)gates[(size_t)grow * 2048 + 1536 + gcol];
                const float cv = cell[(size_t)grow * 512 + gcol];
                const float ncv = fg * cv + ig * cg + 0.1f * v;
                fout[(size_t)grow * 512 + gcol] = og * tanhf(ncv);
                fout[(size_t)Bn * Hn + (size_t)grow * 512 + gcol] = ncv;
            }
        }
    }

    // ---- fused attn write (big-ws path): this block writes attn = E/denom for its
    // row panel and its half of the columns. E re-read is L2/L3-hot from the K-loop.
    if (attnOut) {
        float* sDen = (float*)sA;                   // reuse sA (K-loop fully drained)
        __syncthreads();
        if (wc == 0 && l15 == 0) {
#pragma unroll
            for (int i = 0; i < 2; ++i)
#pragma unroll
                for (int r = 0; r < 4; ++r)
                    sDen[wr * 32 + i * 16 + lr + r] = invd[i][r];
        }
        __syncthreads();
        const int colbase = (col0 == 0) ? 0 : 2048;
        const bf16_t* Eb = E + (size_t)row0 * estride + colbase;
        float* ab = attnOut + (size_t)row0 * 4096 + colbase;
        // 64 rows x 2048 cols; 512 threads, 16B E-read / 32B attn-write per step
        for (int c = tid; c < 64 * 256; c += 512) {
            const int rr = c >> 8, ch = c & 255;
            bf16x8 e8 = *(const bf16x8*)(Eb + (size_t)rr * estride + ch * 8);
            const float inv = sDen[rr];
            float* rp = ab + (size_t)rr * 4096 + ch * 8;
            float4 o0 = { (float)e8[0] * inv, (float)e8[1] * inv,
                          (float)e8[2] * inv, (float)e8[3] * inv };
            float4 o1 = { (float)e8[4] * inv, (float)e8[5] * inv,
                          (float)e8[6] * inv, (float)e8[7] * inv };
            *(float4*)rp = o0;
            *((float4*)rp + 1) = o1;
        }
    }
}

// attn[row] = E[row] / denom[row]. Fallback for the small-ws (packed in d_out) path.
__global__ __launch_bounds__(512)
void attn_writer(const bf16_t* __restrict__ E, int estride,
                 const float* __restrict__ denom, float* __restrict__ attn)
{
    const int row = blockIdx.x * 2 + (threadIdx.x >> 8);
    const int t = threadIdx.x & 255;
    const bf16_t* lp = E + (size_t)row * estride;
    const float inv = 1.0f / denom[row];
    bf16x8 a = ((const bf16x8*)lp)[2 * t];
    bf16x8 b = ((const bf16x8*)lp)[2 * t + 1];
    __syncthreads();
    float* rp = attn + (size_t)row * 4096;
    float4 o0 = { (float)a[0] * inv, (float)a[1] * inv, (float)a[2] * inv, (float)a[3] * inv };
    float4 o1 = { (float)a[4] * inv, (float)a[5] * inv, (float)a[6] * inv, (float)a[7] * inv };
    float4 o2 = { (float)b[0] * inv, (float)b[1] * inv, (float)b[2] * inv, (float)b[3] * inv };
    float4 o3 = { (float)b[4] * inv, (float)b[5] * inv, (float)b[6] * inv, (float)b[7] * inv };
    ((float4*)rp)[4 * t]     = o0;
    ((float4*)rp)[4 * t + 1] = o1;
    ((float4*)rp)[4 * t + 2] = o2;
    ((float4*)rp)[4 * t + 3] = o3;
}

extern "C" void kernel_launch(void* const* d_in, const int* in_sizes, int n_in,
                              void* d_out, int out_size, void* d_ws, size_t ws_size,
                              hipStream_t stream)
{
    const float* input  = (const float*)d_in[0];
    const float* hidden = (const float*)d_in[1];
    const float* cell   = (const float*)d_in[2];
    const float* Wg     = (const float*)d_in[3];
    const float* bg     = (const float*)d_in[4];
    const float* Wa     = (const float*)d_in[5];
    const float* ba     = (const float*)d_in[6];
    const float* Mem    = (const float*)d_in[7];

    float* out  = (float*)d_out;
    float* attn = out + 2ull * Bn * Hn;

    bf16_t* comb  = (bf16_t*)d_ws;                 // [B][1024]      33.5 MB
    bf16_t* WgT   = comb + (size_t)Bn * 1024;      // [2048][1024]    4.2
    bf16_t* WaT   = WgT + (size_t)2048 * 1024;     // [4096][512]     4.2
    bf16_t* MemT  = WaT + (size_t)4096 * 512;      // [512][4096]     4.2
    bf16_t* gates = MemT + (size_t)512 * 4096;     // [B][2048]      67.1
    float*  denom = (float*)(gates + (size_t)Bn * 2048);   // [B] f32   0.07
    bf16_t* pws   = (bf16_t*)(denom + Bn);         // [B][4096]     134.2 (big path)

    const size_t need_big = (size_t)((char*)(pws + (size_t)Bn * 4096) - (char*)d_ws);
    const bool big = ws_size >= need_big;
    bf16_t* Ebuf = big ? pws : (bf16_t*)attn;      // E = exp(logits), bf16
    const int estride = big ? 4096 : 8192;

    // convert + transposes in one launch
    prologue<<<14336, 256, 0, stream>>>(input, hidden, comb, Wg, WgT, Wa, WaT, Mem, MemT);

    // E = exp(h @ Wa + ba): 128x256 tiles, grid 128x16
    gemm_w8<1><<<2048, 512, 0, stream>>>(comb + 512, 1024, WaT, 512, ba, 512, 4096,
                                         Ebuf, estride);
    // gates = act([x|h] @ Wg + bg): 128x256 tiles, grid 128x8
    gemm_w8<0><<<1024, 512, 0, stream>>>(comb, 1024, WgT, 1024, bg, 1024, 2048, gates, 2048);

    // mr = (E @ Mem)/rowsum(E) fused with LSTM update; denom via ones-MFMA.
    // Big-ws path: attn write fused into the tail; small-ws: separate pass.
    gemm3o<<<512, 512, 0, stream>>>(Ebuf, estride, MemT, gates, cell, out, denom,
                                    big ? attn : nullptr);

    if (!big) attn_writer<<<8192, 512, 0, stream>>>(Ebuf, estride, denom, attn);
}